// Round 8
// baseline (42.705 us; speedup 1.0000x reference)
//
#include <hip/hip_runtime.h>
#include <hip/hip_bf16.h>
#include <math.h>

#define BB 2
#define CC 32
#define C8 4
#define NN 4096
#define JG 8          // j-split groups
#define JR (NN/JG)    // 512 keys per flash block
#define VSTRIDE 516   // LDS V row stride in shorts (1032B ≡ 8 mod 128 -> bank-rotated)
#define LOG2E 1.4426950408889634f

typedef __attribute__((ext_vector_type(8))) short short8;
typedef __attribute__((ext_vector_type(16))) float f32x16;

static __device__ __forceinline__ short f2bf(float x) {
    return __builtin_bit_cast(short, __float2bfloat16(x));
}
// round-half-up bf16 pair pack: {bf16(b)|bf16(a)} (a low)
static __device__ __forceinline__ unsigned int pkbf(float a, float b) {
    unsigned int ua = __builtin_bit_cast(unsigned int, a) + 0x8000u;
    unsigned int ub = __builtin_bit_cast(unsigned int, b) + 0x8000u;
    return (ua >> 16) | (ub & 0xffff0000u);
}
static __device__ __forceinline__ short f2bfr(float a) {
    return (short)((__builtin_bit_cast(unsigned int, a) + 0x8000u) >> 16);
}
static __device__ __forceinline__ float bf2f(short s) {
    unsigned int u = ((unsigned int)(unsigned short)s) << 16;
    return __builtin_bit_cast(float, u);
}

// ---------------- K1: QKV projection (blocks 0..31) + CAM gram c<=d (blocks 32..295) ----
__global__ __launch_bounds__(256) void k1(const float* __restrict__ x,
    const float* __restrict__ wq, const float* __restrict__ bq,
    const float* __restrict__ wk, const float* __restrict__ bk,
    const float* __restrict__ wv, const float* __restrict__ bv,
    short* __restrict__ qpk, short* __restrict__ kpk, short* __restrict__ vbf,
    float* __restrict__ eng)
{
    if (blockIdx.x >= 32) {
        // ---- keng: one wave per unordered pair (c<=d); 528 pairs per batch ----
        int w = threadIdx.x >> 6, lane = threadIdx.x & 63;
        int pp = (blockIdx.x - 32)*4 + w;     // 0..1055
        int b = pp >= 528 ? 1 : 0;
        int t = pp - b*528;
        int c = 0, rem = t;
        while (rem >= CC - c) { rem -= CC - c; ++c; }
        int d = c + rem;
        const float4* xc = (const float4*)(x + ((size_t)b*CC + c)*NN);
        const float4* xd = (const float4*)(x + ((size_t)b*CC + d)*NN);
        float s = 0.f;
        for (int tt = lane; tt < NN/4; tt += 64) {
            float4 a = xc[tt], bb = xd[tt];
            s += a.x*bb.x + a.y*bb.y + a.z*bb.z + a.w*bb.w;
        }
        #pragma unroll
        for (int off = 32; off; off >>= 1) s += __shfl_down(s, off, 64);
        if (lane == 0) {
            eng[(b*CC + c)*CC + d] = s;
            eng[(b*CC + d)*CC + c] = s;
        }
        return;
    }
    // ---- kproj: thread = (b,n) ----
    __shared__ float swq[C8*CC], swk[C8*CC], swv[CC*CC], sbq[C8], sbk[C8], sbv[CC];
    int tid = threadIdx.x;
    for (int i = tid; i < C8*CC; i += 256) { swq[i] = wq[i]; swk[i] = wk[i]; }
    for (int i = tid; i < CC*CC; i += 256) swv[i] = wv[i];
    if (tid < C8) { sbq[tid] = bq[tid]; sbk[tid] = bk[tid]; }
    if (tid < CC) sbv[tid] = bv[tid];
    __syncthreads();
    int g = blockIdx.x*256 + tid;         // 0..8191
    int b = g >> 12; int n = g & (NN-1);
    const float* xb = x + (size_t)b*CC*NN + n;
    float xr[CC];
    #pragma unroll
    for (int c = 0; c < CC; ++c) xr[c] = xb[(size_t)c*NN];
    float qv[C8], kv[C8];
    #pragma unroll
    for (int o = 0; o < C8; ++o) { qv[o] = sbq[o]; kv[o] = sbk[o]; }
    #pragma unroll
    for (int c = 0; c < CC; ++c) {
        float xc = xr[c];
        #pragma unroll
        for (int o = 0; o < C8; ++o) { qv[o] += swq[o*CC+c]*xc; kv[o] += swk[o*CC+c]*xc; }
    }
    short4 qs = make_short4(f2bf(qv[0]*LOG2E), f2bf(qv[1]*LOG2E),
                            f2bf(qv[2]*LOG2E), f2bf(qv[3]*LOG2E));
    short4 ks = make_short4(f2bf(kv[0]), f2bf(kv[1]), f2bf(kv[2]), f2bf(kv[3]));
    *(short4*)(qpk + ((size_t)b*NN + n)*4) = qs;
    *(short4*)(kpk + ((size_t)b*NN + n)*4) = ks;
    #pragma unroll
    for (int o = 0; o < CC; ++o) {
        float av = sbv[o];
        #pragma unroll
        for (int c = 0; c < CC; ++c) av += swv[o*CC+c]*xr[c];
        vbf[((size_t)b*CC+o)*NN + n] = f2bf(av);
    }
}

// ---------------- K2: flash PAM, dual-MFMA (blocks 0..511) + Wx fold (512..513) ----
// Wave = 32 queries x 512 keys. K slab fully hoisted to registers (32 VGPR, h==0
// lanes); loop FULLY unrolled: zero global loads inside. V from 32KB LDS slab.
// ppart stored in per-lane register layout: [b][jg][it][w][lane][16] bf16 -> two
// coalesced 16B stores per lane.
__global__ __launch_bounds__(256, 3) void k2(const short* __restrict__ qpk,
    const short* __restrict__ kpk, const short* __restrict__ vbf,
    short* __restrict__ ppart, float* __restrict__ sep,
    const float* __restrict__ eng, const float* __restrict__ wo,
    const float* __restrict__ gc, float* __restrict__ wx)
{
    __shared__ __align__(16) char smem[CC*VSTRIDE*2];   // 33 KB

    if (blockIdx.x >= BB*32*JG) {
        // ---- kwx: CAM softmax folded into Wx, one block per batch ----
        float* se_ = (float*)smem;                // [CC*CC]
        float* sc  = (float*)(smem + CC*CC*4);    // [CC*CC]
        int b = blockIdx.x - BB*32*JG, tid = threadIdx.x;
        for (int i = tid; i < CC*CC; i += 256) se_[i] = eng[b*CC*CC + i];
        __syncthreads();
        if (tid < CC) {
            float mn = se_[tid*CC];
            #pragma unroll
            for (int d = 1; d < CC; ++d) mn = fminf(mn, se_[tid*CC+d]);
            float pv[CC]; float s = 0.f;
            #pragma unroll
            for (int d = 0; d < CC; ++d) { pv[d] = __expf(mn - se_[tid*CC+d]); s += pv[d]; }
            float inv = 1.f/s;
            #pragma unroll
            for (int d = 0; d < CC; ++d) sc[tid*CC+d] = pv[d]*inv;
        }
        __syncthreads();
        float g = gc[0];
        for (int i = tid; i < CC*CC; i += 256) {
            int o = i >> 5, d = i & 31;
            float acc = wo[o*64 + d] + wo[o*64 + 32 + d];
            float t = 0.f;
            #pragma unroll
            for (int c2 = 0; c2 < CC; ++c2) t += wo[o*64 + 32 + c2] * sc[c2*CC + d];
            wx[b*CC*CC + i] = acc + g * t;
        }
        return;
    }

    int blk = blockIdx.x;
    int b = blk >> 8;            // 256 blocks per batch
    int r = blk & 255;
    int it = r >> 3;             // 0..31 (128 queries per block)
    int jg = r & (JG-1);         // 0..7
    int jbase = jg*JR;
    int tid = threadIdx.x;

    // ---- stage V slab [32 rows][512 keys] -> LDS, row stride VSTRIDE ----
    short* vsl = (short*)smem;
    {
        const short* vgp = vbf + (size_t)b*CC*NN + jbase;
        #pragma unroll
        for (int i2 = 0; i2 < 16; ++i2) {
            int idx = tid + i2*256;          // 0..4095 short4 granules
            int rr2 = idx >> 7;              // row 0..31 (128 granules/row)
            int cg  = idx & 127;
            *(short4*)(vsl + rr2*VSTRIDE + cg*4) =
                *(const short4*)(vgp + (size_t)rr2*NN + cg*4);
        }
    }

    int w = tid >> 6, lane = tid & 63;
    int qcol = lane & 31;
    int h = lane >> 5;
    int i0 = it*128 + w*32;

    // Q fragment (B-operand): col=q; contraction elems 0..3 (h==0 lanes) hold q*LOG2E
    short8 qf = {0,0,0,0,0,0,0,0};
    if (h == 0) {
        short4 qv = *(const short4*)(qpk + ((size_t)b*NN + i0 + qcol)*4);
        qf[0]=qv.x; qf[1]=qv.y; qf[2]=qv.z; qf[3]=qv.w;
    }
    // K slab fully hoisted to registers: 16 x short4 (h==0 lanes; zeros on h==1)
    short4 kreg[16];
    #pragma unroll
    for (int t = 0; t < 16; ++t) kreg[t] = make_short4(0,0,0,0);
    if (h == 0) {
        const short* kp0 = kpk + ((size_t)b*NN + jbase + qcol)*4;
        #pragma unroll
        for (int t = 0; t < 16; ++t) kreg[t] = *(const short4*)(kp0 + t*128);
    }
    const short* vrow = vsl + qcol*VSTRIDE;   // PV A-operand row c=lane&31

    f32x16 acc = {0,0,0,0,0,0,0,0,0,0,0,0,0,0,0,0};
    const f32x16 zz = {0,0,0,0,0,0,0,0,0,0,0,0,0,0,0,0};
    float se = 0.f;

    __syncthreads();   // V slab ready

    #pragma unroll
    for (int t = 0; t < 16; ++t) {
        short8 kf = {kreg[t].x, kreg[t].y, kreg[t].z, kreg[t].w, 0,0,0,0};
        f32x16 s = __builtin_amdgcn_mfma_f32_32x32x16_bf16(kf, qf, zz, 0, 0, 0);
        #pragma unroll
        for (int i = 0; i < 16; ++i) s[i] = exp2f(s[i]);
        se += (((s[0]+s[1])+(s[2]+s[3])) + ((s[4]+s[5])+(s[6]+s[7])))
            + (((s[8]+s[9])+(s[10]+s[11])) + ((s[12]+s[13])+(s[14]+s[15])));
        unsigned int u0 = pkbf(s[0],s[1]),   u1 = pkbf(s[2],s[3]);
        unsigned int u2 = pkbf(s[4],s[5]),   u3 = pkbf(s[6],s[7]);
        unsigned int u4 = pkbf(s[8],s[9]),   u5 = pkbf(s[10],s[11]);
        unsigned int u6 = pkbf(s[12],s[13]), u7 = pkbf(s[14],s[15]);
        // V fragments from LDS at permuted key cols k(t,h) = (r&3)+8*(r>>2)+4h
        int vo = t*32 + 4*h;
        short4 a0 = *(const short4*)(vrow + vo);
        short4 a1 = *(const short4*)(vrow + vo + 8);
        short4 a2 = *(const short4*)(vrow + vo + 16);
        short4 a3 = *(const short4*)(vrow + vo + 24);
        short8 vf1 = {a0.x,a0.y,a0.z,a0.w, a1.x,a1.y,a1.z,a1.w};
        short8 pf1 = {(short)u0,(short)(u0>>16),(short)u1,(short)(u1>>16),
                      (short)u2,(short)(u2>>16),(short)u3,(short)(u3>>16)};
        acc = __builtin_amdgcn_mfma_f32_32x32x16_bf16(vf1, pf1, acc, 0, 0, 0);
        short8 vf2 = {a2.x,a2.y,a2.z,a2.w, a3.x,a3.y,a3.z,a3.w};
        short8 pf2 = {(short)u4,(short)(u4>>16),(short)u5,(short)(u5>>16),
                      (short)u6,(short)(u6>>16),(short)u7,(short)(u7>>16)};
        acc = __builtin_amdgcn_mfma_f32_32x32x16_bf16(vf2, pf2, acc, 0, 0, 0);
    }

    se += __shfl_xor(se, 32, 64);   // combine the two key-halves per q

    // ppart register layout: [b][jg][it][w][lane][16] bf16 -> 2 coalesced 16B stores
    short pk[16];
    #pragma unroll
    for (int rr = 0; rr < 16; ++rr) pk[rr] = f2bfr(acc[rr]);
    short* pb = ppart + (size_t)(b*JG + jg)*NN*CC
              + ((size_t)(it*4 + w)*64 + lane)*16;
    *(short8*)(pb)     = *(short8*)(pk);
    *(short8*)(pb + 8) = *(short8*)(pk + 8);
    if (h == 0) sep[((size_t)(b*JG + jg))*NN + i0 + qcol] = se;
}

// ---------------- K3: combine partials + output projection (thread = token) ----
__global__ __launch_bounds__(64) void kout(const short* __restrict__ ppart,
    const float* __restrict__ sep,
    const float* __restrict__ x, const float* __restrict__ wo,
    const float* __restrict__ bo, const float* __restrict__ gp,
    const float* __restrict__ wx, float* __restrict__ out)
{
    __shared__ float sw1[CC*CC], swx[CC*CC], sbo[CC];
    int blk = blockIdx.x;               // 128 blocks
    int b = blk >> 6;                   // 64 blocks per batch
    int n = (blk & 63)*64 + threadIdx.x;
    float g = gp[0];
    for (int i = threadIdx.x; i < CC*CC; i += 64) {
        int o = i >> 5, c2 = i & 31;
        sw1[i] = g * wo[o*64 + c2];
        swx[i] = wx[b*CC*CC + i];
    }
    if (threadIdx.x < CC) sbo[threadIdx.x] = bo[threadIdx.x];
    __syncthreads();

    int it = n >> 7, w = (n >> 5) & 3, qcol = n & 31;
    size_t loff = ((size_t)(it*4 + w)*64 + qcol)*16;
    const short* pbase = ppart + (size_t)b*JG*NN*CC + loff;
    const float* sb = sep + (size_t)b*JG*NN + n;

    float acc[CC]; float se = 0.f;
    #pragma unroll
    for (int c = 0; c < CC; ++c) acc[c] = 0.f;
    #pragma unroll
    for (int jg = 0; jg < JG; ++jg) {
        const short* pr = pbase + (size_t)jg*NN*CC;
        short8 lo0 = *(const short8*)(pr);        // h=0, rr 0..7
        short8 hi0 = *(const short8*)(pr + 8);    // h=0, rr 8..15
        short8 lo1 = *(const short8*)(pr + 512);  // h=1 (lane+32), rr 0..7
        short8 hi1 = *(const short8*)(pr + 520);  // h=1, rr 8..15
        #pragma unroll
        for (int e = 0; e < 8; ++e) {
            int c0 = (e&3) + 8*(e>>2);            // c for (h=0, rr=e)
            acc[c0]      += bf2f(lo0[e]);
            acc[c0+4]    += bf2f(lo1[e]);
            acc[c0+16]   += bf2f(hi0[e]);
            acc[c0+20]   += bf2f(hi1[e]);
        }
        se += sb[(size_t)jg*NN];
    }
    float inv = 1.f/se;
    float o_[CC];
    #pragma unroll
    for (int o = 0; o < CC; ++o) o_[o] = sbo[o];
    #pragma unroll
    for (int c = 0; c < CC; ++c) {
        float pc = acc[c]*inv;
        #pragma unroll
        for (int o = 0; o < CC; ++o) o_[o] += sw1[o*CC+c]*pc;
    }
    const float* xb = x + (size_t)b*CC*NN + n;
    #pragma unroll
    for (int d = 0; d < CC; ++d) {
        float xd = xb[(size_t)d*NN];
        #pragma unroll
        for (int o = 0; o < CC; ++o) o_[o] += swx[o*CC+d]*xd;
    }
    float* ob = out + (size_t)b*CC*NN + n;
    #pragma unroll
    for (int o = 0; o < CC; ++o) ob[(size_t)o*NN] = o_[o];
}

extern "C" void kernel_launch(void* const* d_in, const int* in_sizes, int n_in,
                              void* d_out, int out_size, void* d_ws, size_t ws_size,
                              hipStream_t stream)
{
    const float* x  = (const float*)d_in[0];
    const float* wq = (const float*)d_in[1];
    const float* bq = (const float*)d_in[2];
    const float* wk = (const float*)d_in[3];
    const float* bk = (const float*)d_in[4];
    const float* wv = (const float*)d_in[5];
    const float* bv = (const float*)d_in[6];
    const float* gp = (const float*)d_in[7];
    const float* gc = (const float*)d_in[8];
    const float* wo = (const float*)d_in[9];
    const float* bo = (const float*)d_in[10];

    short* qpk = (short*)d_ws;             // B*N*4   = 32768 sh
    short* kpk = qpk + 32768;              // 32768 sh
    short* vbf = kpk + 32768;              // B*C*N   = 262144 sh
    float* eng = (float*)(vbf + 262144);   // 2048 f
    float* wx  = eng + 2048;               // 2048 f
    float* sep = wx + 2048;                // B*JG*N  = 65536 f
    short* ppart = (short*)(sep + 65536);  // B*JG*C*N = 2097152 sh (~5 MB total)

    k1<<<296, 256, 0, stream>>>(x, wq, bq, wk, bk, wv, bv, qpk, kpk, vbf, eng);
    k2<<<BB*32*JG + BB, 256, 0, stream>>>(qpk, kpk, vbf, ppart, sep, eng, wo, gc, wx);
    kout<<<128, 64, 0, stream>>>(ppart, sep, x, wo, bo, gp, wx, (float*)d_out);
}